// Round 1
// baseline (850.724 us; speedup 1.0000x reference)
//
#include <hip/hip_runtime.h>
#include <cstddef>

#define S_LEN  2048
#define DMODEL 1024
#define NHEADS 16
#define DKV    64

// ---------------- fp32 tiled GEMM: C[M,N] = A[M,K] @ B[K,N] ----------------
// 64x64 tile, 256 threads, 4x4 per thread, K-chunks of 16.
#define GT  64
#define GKT 16

__global__ __launch_bounds__(256) void gemm_f32(
    const float* __restrict__ A, const float* __restrict__ B,
    float* __restrict__ C, int M, int N, int K)
{
    // As stored transposed [k][m], pad +4 floats: keeps 16B alignment for
    // float4 reads AND makes the store pattern 2-way-conflict (free).
    __shared__ float As[GKT][GT + 4];
    __shared__ float Bs[GKT][GT];

    const int tid = threadIdx.x;
    const int tx  = tid & 15;   // n direction (4 cols each)
    const int ty  = tid >> 4;   // m direction (4 rows each)
    const int m0  = blockIdx.y * GT;
    const int n0  = blockIdx.x * GT;

    float acc[4][4] = {};

    for (int k0 = 0; k0 < K; k0 += GKT) {
        // A tile: 64 rows x 16 k — coalesced in 64B chunks, store transposed
        #pragma unroll
        for (int i = 0; i < 4; i++) {
            int idx = tid + i * 256;
            int r = idx >> 4, c = idx & 15;
            As[c][r] = A[(size_t)(m0 + r) * K + (k0 + c)];
        }
        // B tile: 16 k x 64 cols — coalesced
        #pragma unroll
        for (int i = 0; i < 4; i++) {
            int idx = tid + i * 256;
            int r = idx >> 6, c = idx & 63;
            Bs[r][c] = B[(size_t)(k0 + r) * N + (n0 + c)];
        }
        __syncthreads();

        #pragma unroll
        for (int kk = 0; kk < GKT; kk++) {
            float4 a4 = *(const float4*)&As[kk][ty * 4];
            float4 b4 = *(const float4*)&Bs[kk][tx * 4];
            float a[4] = {a4.x, a4.y, a4.z, a4.w};
            float b[4] = {b4.x, b4.y, b4.z, b4.w};
            #pragma unroll
            for (int i = 0; i < 4; i++)
                #pragma unroll
                for (int j = 0; j < 4; j++)
                    acc[i][j] += a[i] * b[j];
        }
        __syncthreads();
    }

    #pragma unroll
    for (int i = 0; i < 4; i++) {
        float4 o = {acc[i][0], acc[i][1], acc[i][2], acc[i][3]};
        *(float4*)&C[(size_t)(m0 + ty * 4 + i) * N + n0 + tx * 4] = o;
    }
}

// ---------------- flash-style fused attention (fp32) ----------------
// Grid: (S/BQ, NHEADS). Block: 256 threads.
// Thread (tq = tid>>2, part = tid&3): query row tq of the tile, owns output
// dims [part*16, part*16+16). Online softmax state (m, l) kept redundantly
// per part — computed from identical LDS data in identical order, so all 4
// copies are bit-identical (no cross-part reduction needed).
#define BQ   64
#define BK   64
#define LSTR 68   // LDS row stride: 2-way max bank conflicts, 16B aligned

__device__ __forceinline__ int rel_bucket(int rp) {
    // Exact integer version of the T5 bidirectional bucket
    // (NUM_BUCKETS=32, MAX_DISTANCE=128): for |rp|>=8,
    // 8 + floor(log(|rp|/8)/log(16) * 8) == 33 - clz(rp*rp).
    int arp = rp < 0 ? -rp : rp;
    int bucket;
    if (arp < 8) {
        bucket = arp;
    } else {
        int lgb = 33 - __clz(arp * arp);   // arp <= 2047 -> arp^2 < 2^22
        bucket = lgb < 15 ? lgb : 15;
    }
    return rp > 0 ? bucket + 16 : bucket;
}

__global__ __launch_bounds__(256) void attn_kernel(
    const float* __restrict__ Q, const float* __restrict__ K,
    const float* __restrict__ V, float* __restrict__ CTX,
    const float* __restrict__ rel_bias)
{
    __shared__ float Ks[BK][LSTR];
    __shared__ float Vs[BK][LSTR];
    __shared__ float Ps[BQ][LSTR];
    __shared__ float biasH[32];

    const int h    = blockIdx.y;
    const int q0   = blockIdx.x * BQ;
    const int tid  = threadIdx.x;
    const int tq   = tid >> 2;
    const int part = tid & 3;

    if (tid < 32) biasH[tid] = rel_bias[tid * NHEADS + h];

    // Full q row in registers (64 VGPRs); 4 parts read the same row (L1/L2 hit).
    float qreg[64];
    {
        const float* qrow = Q + (size_t)(q0 + tq) * DMODEL + h * DKV;
        #pragma unroll
        for (int i = 0; i < 16; i++) {
            float4 t = *(const float4*)(qrow + 4 * i);
            qreg[4*i+0] = t.x; qreg[4*i+1] = t.y;
            qreg[4*i+2] = t.z; qreg[4*i+3] = t.w;
        }
    }

    float m = -3.0e38f, l = 0.0f;
    float O[16] = {0.f,0.f,0.f,0.f,0.f,0.f,0.f,0.f,
                   0.f,0.f,0.f,0.f,0.f,0.f,0.f,0.f};

    for (int k0 = 0; k0 < S_LEN; k0 += BK) {
        __syncthreads();   // prev-iter LDS reads done (also covers biasH init)

        // Stage K/V chunk: each thread 16 floats of one row, coalesced 256B.
        {
            const float* krow = K + (size_t)(k0 + tq) * DMODEL + h * DKV + part * 16;
            const float* vrow = V + (size_t)(k0 + tq) * DMODEL + h * DKV + part * 16;
            #pragma unroll
            for (int i = 0; i < 4; i++) {
                *(float4*)&Ks[tq][part * 16 + 4 * i] = *(const float4*)(krow + 4 * i);
                *(float4*)&Vs[tq][part * 16 + 4 * i] = *(const float4*)(vrow + 4 * i);
            }
        }
        __syncthreads();

        // Scores: thread covers keys j = jj*4 + part (interleaved so the 4
        // parts' Ks-row reads hit 4 distinct banks).
        #pragma unroll 2
        for (int jj = 0; jj < 16; jj++) {
            int j = jj * 4 + part;
            float s = 0.0f;
            #pragma unroll
            for (int d4 = 0; d4 < 16; d4++) {
                float4 k4 = *(const float4*)&Ks[j][4 * d4];
                s += qreg[4*d4+0] * k4.x + qreg[4*d4+1] * k4.y
                   + qreg[4*d4+2] * k4.z + qreg[4*d4+3] * k4.w;
            }
            int rp = (k0 + j) - (q0 + tq);
            s += biasH[rel_bucket(rp)];
            Ps[tq][j] = s;
        }
        __syncthreads();

        // Row max (redundant across parts — deterministic, identical).
        float mc = -3.0e38f;
        #pragma unroll
        for (int j4 = 0; j4 < 16; j4++) {
            float4 p4 = *(const float4*)&Ps[tq][4 * j4];
            mc = fmaxf(mc, fmaxf(fmaxf(p4.x, p4.y), fmaxf(p4.z, p4.w)));
        }
        float m_new = fmaxf(m, mc);
        float alpha = __expf(m - m_new);

        // exp in place (each part its own 16 keys)
        #pragma unroll
        for (int jj = 0; jj < 16; jj++) {
            int j = jj * 4 + part;
            Ps[tq][j] = __expf(Ps[tq][j] - m_new);
        }
        __syncthreads();

        // Row sum (redundant, fixed order -> identical across parts).
        float lc = 0.0f;
        #pragma unroll
        for (int j4 = 0; j4 < 16; j4++) {
            float4 p4 = *(const float4*)&Ps[tq][4 * j4];
            lc += p4.x + p4.y + p4.z + p4.w;
        }
        l = l * alpha + lc;
        m = m_new;

        #pragma unroll
        for (int i = 0; i < 16; i++) O[i] *= alpha;

        // O += P @ V  (thread's 16 dims)
        #pragma unroll 4
        for (int j = 0; j < BK; j++) {
            float p = Ps[tq][j];
            #pragma unroll
            for (int ii = 0; ii < 4; ii++) {
                float4 v4 = *(const float4*)&Vs[j][part * 16 + 4 * ii];
                O[4*ii+0] += p * v4.x;
                O[4*ii+1] += p * v4.y;
                O[4*ii+2] += p * v4.z;
                O[4*ii+3] += p * v4.w;
            }
        }
    }

    const float inv_l = 1.0f / l;
    float* crow = CTX + (size_t)(q0 + tq) * DMODEL + h * DKV + part * 16;
    #pragma unroll
    for (int ii = 0; ii < 4; ii++) {
        float4 o = {O[4*ii+0] * inv_l, O[4*ii+1] * inv_l,
                    O[4*ii+2] * inv_l, O[4*ii+3] * inv_l};
        *(float4*)(crow + 4 * ii) = o;
    }
}

// ---------------- launch ----------------
extern "C" void kernel_launch(void* const* d_in, const int* in_sizes, int n_in,
                              void* d_out, int out_size, void* d_ws, size_t ws_size,
                              hipStream_t stream) {
    const float* X  = (const float*)d_in[0];   // [1, 2048, 1024]
    const float* Wq = (const float*)d_in[1];   // [1024, 1024]
    const float* Wk = (const float*)d_in[2];
    const float* Wv = (const float*)d_in[3];
    const float* Wo = (const float*)d_in[4];
    const float* rb = (const float*)d_in[5];   // [32, 16]
    float* out = (float*)d_out;                // [1, 2048, 1024] fp32
    float* ws  = (float*)d_ws;

    const size_t SZ = (size_t)S_LEN * DMODEL;
    float* Qb = ws;            // 8 MB each; total 32 MB of workspace
    float* Kb = ws + SZ;
    float* Vb = ws + 2 * SZ;
    float* Cb = ws + 3 * SZ;

    dim3 blk(256);
    dim3 ggrid(DMODEL / GT, S_LEN / GT);   // 16 x 32 = 512 blocks

    gemm_f32<<<ggrid, blk, 0, stream>>>(X,  Wq, Qb, S_LEN, DMODEL, DMODEL);
    gemm_f32<<<ggrid, blk, 0, stream>>>(X,  Wk, Kb, S_LEN, DMODEL, DMODEL);
    gemm_f32<<<ggrid, blk, 0, stream>>>(X,  Wv, Vb, S_LEN, DMODEL, DMODEL);

    attn_kernel<<<dim3(S_LEN / BQ, NHEADS), blk, 0, stream>>>(Qb, Kb, Vb, Cb, rb);

    gemm_f32<<<ggrid, blk, 0, stream>>>(Cb, Wo, out, S_LEN, DMODEL, DMODEL);
}

// Round 2
// 217.498 us; speedup vs baseline: 3.9114x; 3.9114x over previous
//
#include <hip/hip_runtime.h>
#include <cstddef>
#include <cstdint>

typedef float  f32x4  __attribute__((ext_vector_type(4)));
typedef __bf16 bf16x8 __attribute__((ext_vector_type(8)));
typedef unsigned short ushort_t;
typedef unsigned int __attribute__((address_space(1))) u32_g;
typedef unsigned int __attribute__((address_space(3))) u32_l;

#define S_LEN  2048
#define DMODEL 1024
#define NH     16
#define QKV_LD 3072   // fused QKV row stride (Q|K|V)

static __device__ __forceinline__ ushort_t f2bf(float f) {
    union { float f; unsigned u; } v; v.f = f;
    unsigned r = (v.u + 0x7FFFu + ((v.u >> 16) & 1u)) >> 16;
    return (ushort_t)r;
}
static __device__ __forceinline__ float bf2f(ushort_t b) {
    union { unsigned u; float f; } v; v.u = ((unsigned)b) << 16;
    return v.f;
}
// async 16B global->LDS; lds dst = wave-uniform base + lane*16
static __device__ __forceinline__ void load_lds16(const void* g, void* l) {
    __builtin_amdgcn_global_load_lds((const u32_g*)g, (u32_l*)l, 16, 0, 0);
}

// ---------------- cast X (fp32 -> bf16), elementwise ----------------
__global__ __launch_bounds__(256) void cast_x(const float* __restrict__ X,
                                              ushort_t* __restrict__ Xb, int n4) {
    int i = blockIdx.x * 256 + threadIdx.x;
    if (i < n4) {
        float4 v = ((const float4*)X)[i];
        ushort4 o = make_ushort4(f2bf(v.x), f2bf(v.y), f2bf(v.z), f2bf(v.w));
        ((ushort4*)Xb)[i] = o;
    }
}

// ------------- weight transpose+cast: W[k][n] fp32 -> W^T[n][k] bf16 -------------
__global__ __launch_bounds__(256) void wcast(
    const float* __restrict__ Wq, const float* __restrict__ Wk,
    const float* __restrict__ Wv, const float* __restrict__ Wo,
    ushort_t* __restrict__ Wt, ushort_t* __restrict__ Wot)
{
    __shared__ float T[64][68];   // 68: 16B-aligned rows, bank-shifted
    const int z = blockIdx.z;
    const float* W = (z == 0) ? Wq : (z == 1) ? Wk : (z == 2) ? Wv : Wo;
    ushort_t* Out = (z == 3) ? Wot : (Wt + (size_t)z * 1024 * 1024);
    const int k0 = blockIdx.y * 64, n0 = blockIdx.x * 64;
    const int t = threadIdx.x;
    #pragma unroll
    for (int i = 0; i < 4; i++) {
        int g = i * 256 + t; int kl = g >> 4, ng = g & 15;
        float4 v = *(const float4*)&W[(size_t)(k0 + kl) * 1024 + n0 + ng * 4];
        *(float4*)&T[kl][ng * 4] = v;
    }
    __syncthreads();
    #pragma unroll
    for (int i = 0; i < 2; i++) {
        int g = i * 256 + t; int nl = g >> 3, kg = g & 7;
        alignas(16) ushort_t pk[8];
        #pragma unroll
        for (int j = 0; j < 8; j++) pk[j] = f2bf(T[kg * 8 + j][nl]);
        *(uint4*)&Out[(size_t)(n0 + nl) * 1024 + k0 + kg * 8] = *(uint4*)pk;
    }
}

// ------------- per-head V transpose: QKV V-section -> Vt[h][d][s] bf16 -------------
__global__ __launch_bounds__(256) void vt_trans(const ushort_t* __restrict__ QKV,
                                                ushort_t* __restrict__ Vt) {
    __shared__ ushort_t T[64][80];   // 160B rows: 16B aligned
    const int h = blockIdx.y, s0 = blockIdx.x * 64;
    const int t = threadIdx.x;
    #pragma unroll
    for (int i = 0; i < 2; i++) {
        int g = i * 256 + t; int sl = g >> 3, dg = g & 7;
        *(uint4*)&T[sl][dg * 8] =
            *(const uint4*)&QKV[(size_t)(s0 + sl) * QKV_LD + 2048 + h * 64 + dg * 8];
    }
    __syncthreads();
    #pragma unroll
    for (int i = 0; i < 2; i++) {
        int g = i * 256 + t; int dl = g >> 3, sg = g & 7;
        alignas(16) ushort_t pk[8];
        #pragma unroll
        for (int j = 0; j < 8; j++) pk[j] = T[sg * 8 + j][dl];
        *(uint4*)&Vt[(size_t)(h * 64 + dl) * S_LEN + s0 + sg * 8] = *(uint4*)pk;
    }
}

// ---------------- bf16 MFMA GEMM: C[M,N] = A[M,K] @ B^T (B given [N][K]) ----------------
// 128x128 tile, BK=64, 4 waves (2x2), each wave 64x64 = 4x4 MFMA tiles.
// LDS XOR-swizzled (granule ^= row&7) -> conflict-free frag reads.
template <int BF16OUT>
__global__ __launch_bounds__(256) void gemm_bf16(
    const ushort_t* __restrict__ A, const ushort_t* __restrict__ B,
    void* __restrict__ Cout, int M, int N, int K)
{
    __shared__ ushort_t As[128 * 64];  // [m][kgran swizzled], 16 KB
    __shared__ ushort_t Bs[128 * 64];
    const int tid = threadIdx.x;
    const int w = tid >> 6, lane = tid & 63, quad = lane >> 4, cid = lane & 15;
    const int wm = w >> 1, wn = w & 1;
    const int m0 = blockIdx.y * 128, n0 = blockIdx.x * 128;

    f32x4 acc[4][4] = {};

    for (int k0 = 0; k0 < K; k0 += 64) {
        #pragma unroll
        for (int i = 0; i < 4; i++) {
            int g = i * 256 + tid; int r = g >> 3, kg = g & 7;
            int dg = kg ^ (r & 7);
            load_lds16(A + (size_t)(m0 + r) * K + k0 + dg * 8, &As[(i * 256 + w * 64) * 8]);
            load_lds16(B + (size_t)(n0 + r) * K + k0 + dg * 8, &Bs[(i * 256 + w * 64) * 8]);
        }
        __syncthreads();
        #pragma unroll
        for (int kk = 0; kk < 2; kk++) {
            bf16x8 af[4], bf[4];
            #pragma unroll
            for (int t = 0; t < 4; t++) {
                int m = wm * 64 + t * 16 + cid;
                af[t] = *(const bf16x8*)&As[m * 64 + (((kk * 4 + quad) ^ (m & 7)) * 8)];
                int n = wn * 64 + t * 16 + cid;
                bf[t] = *(const bf16x8*)&Bs[n * 64 + (((kk * 4 + quad) ^ (n & 7)) * 8)];
            }
            #pragma unroll
            for (int i = 0; i < 4; i++)
                #pragma unroll
                for (int j = 0; j < 4; j++)
                    acc[i][j] = __builtin_amdgcn_mfma_f32_16x16x32_bf16(af[i], bf[j], acc[i][j], 0, 0, 0);
        }
        __syncthreads();
    }
    #pragma unroll
    for (int i = 0; i < 4; i++)
        #pragma unroll
        for (int j = 0; j < 4; j++)
            #pragma unroll
            for (int r = 0; r < 4; r++) {
                int row = m0 + wm * 64 + i * 16 + quad * 4 + r;
                int col = n0 + wn * 64 + j * 16 + cid;
                float v = acc[i][j][r];
                if (BF16OUT) ((ushort_t*)Cout)[(size_t)row * N + col] = f2bf(v);
                else         ((float*)Cout)[(size_t)row * N + col] = v;
            }
}

// ---------------- MFMA flash attention ----------------
// Block: 1 head x 64 queries, 4 waves (16 q-rows each). K-chunks of 64.
__global__ __launch_bounds__(256) void attn_mfma(
    const ushort_t* __restrict__ QKV, const ushort_t* __restrict__ Vt,
    const float* __restrict__ rel_bias, ushort_t* __restrict__ Ctx)
{
    __shared__ ushort_t Ks[64 * 64];     // [key][dgran ^ key&7]      8 KB
    __shared__ ushort_t Vs[64 * 64];     // [d][keygran ^ d&7]        8 KB
    __shared__ ushort_t Ps[4][16 * 64];  // per-wave [q][kgran ^ q&7] 8 KB
    __shared__ float biasH[32];

    const int tid = threadIdx.x;
    const int w = tid >> 6, lane = tid & 63, quad = lane >> 4, cid = lane & 15;
    const int h = blockIdx.y, q0 = blockIdx.x * 64;
    const int qg = q0 + w * 16 + cid;    // this lane's A-operand q row

    if (tid < 32) biasH[tid] = rel_bias[tid * NH + h];

    bf16x8 qf[2];
    #pragma unroll
    for (int kk = 0; kk < 2; kk++)
        qf[kk] = *(const bf16x8*)&QKV[(size_t)qg * QKV_LD + h * 64 + kk * 32 + quad * 8];

    float mrow[4] = {-3e38f, -3e38f, -3e38f, -3e38f};
    float lrow[4] = {0.f, 0.f, 0.f, 0.f};
    f32x4 Oacc[4] = {};   // [dt]: rows quad*4+r, col dt*16+cid

    for (int k0 = 0; k0 < S_LEN; k0 += 64) {
        __syncthreads();   // prior chunk's Ks/Vs reads done (1st iter: biasH)
        #pragma unroll
        for (int i = 0; i < 2; i++) {
            int g = i * 256 + tid; int row = g >> 3, kg = g & 7;
            load_lds16(QKV + (size_t)(k0 + row) * QKV_LD + 1024 + h * 64 + ((kg ^ (row & 7)) * 8),
                       &Ks[(i * 256 + w * 64) * 8]);
            load_lds16(Vt + (size_t)(h * 64 + row) * S_LEN + k0 + ((kg ^ (row & 7)) * 8),
                       &Vs[(i * 256 + w * 64) * 8]);
        }
        __syncthreads();

        // S = Q K^T  (per wave: 16q x 64key in 4 tiles)
        f32x4 S[4] = {};
        #pragma unroll
        for (int kk = 0; kk < 2; kk++)
            #pragma unroll
            for (int tj = 0; tj < 4; tj++) {
                int key = tj * 16 + cid;
                bf16x8 kf = *(const bf16x8*)&Ks[key * 64 + (((kk * 4 + quad) ^ (key & 7)) * 8)];
                S[tj] = __builtin_amdgcn_mfma_f32_16x16x32_bf16(qf[kk], kf, S[tj], 0, 0, 0);
            }

        // bias + online softmax (lane owns rows q_loc = quad*4+r, keys tj*16+cid)
        #pragma unroll
        for (int r = 0; r < 4; r++) {
            int q_glob = q0 + w * 16 + quad * 4 + r;
            float mx = -3e38f;
            #pragma unroll
            for (int tj = 0; tj < 4; tj++) {
                int rp = (k0 + tj * 16 + cid) - q_glob;
                int arp = rp < 0 ? -rp : rp;
                int bucket;
                if (arp < 8) bucket = arp;
                else { int lg = 33 - __clz(arp * arp); bucket = lg < 15 ? lg : 15; }
                if (rp > 0) bucket += 16;
                float s = S[tj][r] + biasH[bucket];
                S[tj][r] = s;
                mx = fmaxf(mx, s);
            }
            mx = fmaxf(mx, __shfl_xor(mx, 1));
            mx = fmaxf(mx, __shfl_xor(mx, 2));
            mx = fmaxf(mx, __shfl_xor(mx, 4));
            mx = fmaxf(mx, __shfl_xor(mx, 8));
            float mn = fmaxf(mrow[r], mx);
            float alpha = __expf(mrow[r] - mn);
            mrow[r] = mn;
            float psum = 0.f;
            int qloc = quad * 4 + r;
            #pragma unroll
            for (int tj = 0; tj < 4; tj++) {
                float p = __expf(S[tj][r] - mn);
                ushort_t pb = f2bf(p);
                psum += bf2f(pb);
                int kgr = (tj * 2 + (cid >> 3)) ^ (qloc & 7);
                Ps[w][qloc * 64 + kgr * 8 + (cid & 7)] = pb;
            }
            psum += __shfl_xor(psum, 1);
            psum += __shfl_xor(psum, 2);
            psum += __shfl_xor(psum, 4);
            psum += __shfl_xor(psum, 8);
            lrow[r] = lrow[r] * alpha + psum;
            #pragma unroll
            for (int dt = 0; dt < 4; dt++) Oacc[dt][r] *= alpha;
        }
        __syncthreads();   // Ps cross-lane visibility before A-operand reads

        // O += P @ V
        #pragma unroll
        for (int kk = 0; kk < 2; kk++) {
            bf16x8 pf = *(const bf16x8*)&Ps[w][cid * 64 + (((kk * 4 + quad) ^ (cid & 7)) * 8)];
            #pragma unroll
            for (int dt = 0; dt < 4; dt++) {
                int d = dt * 16 + cid;
                bf16x8 vf = *(const bf16x8*)&Vs[d * 64 + (((kk * 4 + quad) ^ (d & 7)) * 8)];
                Oacc[dt] = __builtin_amdgcn_mfma_f32_16x16x32_bf16(pf, vf, Oacc[dt], 0, 0, 0);
            }
        }
    }

    #pragma unroll
    for (int r = 0; r < 4; r++) {
        float inv = 1.f / lrow[r];
        int row = q0 + w * 16 + quad * 4 + r;
        #pragma unroll
        for (int dt = 0; dt < 4; dt++)
            Ctx[(size_t)row * DMODEL + h * 64 + dt * 16 + cid] = f2bf(Oacc[dt][r] * inv);
    }
}

// ---------------- launch ----------------
extern "C" void kernel_launch(void* const* d_in, const int* in_sizes, int n_in,
                              void* d_out, int out_size, void* d_ws, size_t ws_size,
                              hipStream_t stream) {
    const float* X  = (const float*)d_in[0];
    const float* Wq = (const float*)d_in[1];
    const float* Wk = (const float*)d_in[2];
    const float* Wv = (const float*)d_in[3];
    const float* Wo = (const float*)d_in[4];
    const float* rb = (const float*)d_in[5];
    float* out = (float*)d_out;

    ushort_t* ws = (ushort_t*)d_ws;
    const size_t M1 = 1024 * 1024;
    ushort_t* Xb  = ws;             // 2M elems (4 MB); reused as Ctx after QKV GEMM
    ushort_t* Wt  = ws + 2 * M1;    // 3M elems (6 MB)  [3072][1024] = Wq^T|Wk^T|Wv^T
    ushort_t* Wot = ws + 5 * M1;    // 1M elems (2 MB)
    ushort_t* QKV = ws + 6 * M1;    // 6M elems (12 MB) [2048][3072] bf16
    ushort_t* Vt  = ws + 12 * M1;   // 2M elems (4 MB)  [16][64][2048]
    ushort_t* Ctx = Xb;             // alias: Xb dead after gemm_qkv

    cast_x<<<dim3((S_LEN * DMODEL / 4 + 255) / 256), 256, 0, stream>>>(X, Xb, S_LEN * DMODEL / 4);
    wcast<<<dim3(16, 16, 4), 256, 0, stream>>>(Wq, Wk, Wv, Wo, Wt, Wot);
    gemm_bf16<1><<<dim3(24, 16), 256, 0, stream>>>(Xb, Wt, QKV, S_LEN, 3072, DMODEL);
    vt_trans<<<dim3(32, 16), 256, 0, stream>>>(QKV, Vt);
    attn_mfma<<<dim3(32, 16), 256, 0, stream>>>(QKV, Vt, rb, Ctx);
    gemm_bf16<0><<<dim3(8, 16), 256, 0, stream>>>(Ctx, Wot, out, S_LEN, DMODEL, DMODEL);
}

// Round 3
// 172.581 us; speedup vs baseline: 4.9294x; 1.2603x over previous
//
#include <hip/hip_runtime.h>
#include <cstddef>
#include <cstdint>

typedef float  f32x4  __attribute__((ext_vector_type(4)));
typedef __bf16 bf16x8 __attribute__((ext_vector_type(8)));
typedef unsigned short ushort_t;
typedef unsigned int __attribute__((address_space(1))) u32_g;
typedef unsigned int __attribute__((address_space(3))) u32_l;

#define S_LEN  2048
#define DMODEL 1024
#define NH     16
#define QKV_LD 3072   // fused QKV row stride (Q|K|V)

static __device__ __forceinline__ ushort_t f2bf(float f) {
    union { float f; unsigned u; } v; v.f = f;
    unsigned r = (v.u + 0x7FFFu + ((v.u >> 16) & 1u)) >> 16;
    return (ushort_t)r;
}
// fast round-to-nearest (no tie-even) — valid for positive finite p
static __device__ __forceinline__ ushort_t f2bf_rn(float f) {
    union { float f; unsigned u; } v; v.f = f;
    return (ushort_t)((v.u + 0x8000u) >> 16);
}
// async 16B global->LDS; lds dst = wave-uniform base + lane*16
static __device__ __forceinline__ void load_lds16(const void* g, void* l) {
    __builtin_amdgcn_global_load_lds((const u32_g*)g, (u32_l*)l, 16, 0, 0);
}
static __device__ __forceinline__ int rel_bucket(int rp) {
    int arp = rp < 0 ? -rp : rp;
    int bucket;
    if (arp < 8) bucket = arp;
    else { int lg = 33 - __clz(arp * arp); bucket = lg < 15 ? lg : 15; }
    return rp > 0 ? bucket + 16 : bucket;
}

// ---------------- cast X (fp32 -> bf16), elementwise ----------------
__global__ __launch_bounds__(256) void cast_x(const float* __restrict__ X,
                                              ushort_t* __restrict__ Xb, int n4) {
    int i = blockIdx.x * 256 + threadIdx.x;
    if (i < n4) {
        float4 v = ((const float4*)X)[i];
        ushort4 o = make_ushort4(f2bf(v.x), f2bf(v.y), f2bf(v.z), f2bf(v.w));
        ((ushort4*)Xb)[i] = o;
    }
}

// ------------- weight transpose+cast: W[k][n] fp32 -> W^T[n][k] bf16 -------------
__global__ __launch_bounds__(256) void wcast(
    const float* __restrict__ Wq, const float* __restrict__ Wk,
    const float* __restrict__ Wv, const float* __restrict__ Wo,
    ushort_t* __restrict__ Wt, ushort_t* __restrict__ Wot)
{
    __shared__ float T[64][68];
    const int z = blockIdx.z;
    const float* W = (z == 0) ? Wq : (z == 1) ? Wk : (z == 2) ? Wv : Wo;
    ushort_t* Out = (z == 3) ? Wot : (Wt + (size_t)z * 1024 * 1024);
    const int k0 = blockIdx.y * 64, n0 = blockIdx.x * 64;
    const int t = threadIdx.x;
    #pragma unroll
    for (int i = 0; i < 4; i++) {
        int g = i * 256 + t; int kl = g >> 4, ng = g & 15;
        float4 v = *(const float4*)&W[(size_t)(k0 + kl) * 1024 + n0 + ng * 4];
        *(float4*)&T[kl][ng * 4] = v;
    }
    __syncthreads();
    #pragma unroll
    for (int i = 0; i < 2; i++) {
        int g = i * 256 + t; int nl = g >> 3, kg = g & 7;
        alignas(16) ushort_t pk[8];
        #pragma unroll
        for (int j = 0; j < 8; j++) pk[j] = f2bf(T[kg * 8 + j][nl]);
        *(uint4*)&Out[(size_t)(n0 + nl) * 1024 + k0 + kg * 8] = *(uint4*)pk;
    }
}

// ------------- per-head V transpose: QKV V-section -> Vt[h][d][s] bf16 -------------
__global__ __launch_bounds__(256) void vt_trans(const ushort_t* __restrict__ QKV,
                                                ushort_t* __restrict__ Vt) {
    __shared__ ushort_t T[64][80];
    const int h = blockIdx.y, s0 = blockIdx.x * 64;
    const int t = threadIdx.x;
    #pragma unroll
    for (int i = 0; i < 2; i++) {
        int g = i * 256 + t; int sl = g >> 3, dg = g & 7;
        *(uint4*)&T[sl][dg * 8] =
            *(const uint4*)&QKV[(size_t)(s0 + sl) * QKV_LD + 2048 + h * 64 + dg * 8];
    }
    __syncthreads();
    #pragma unroll
    for (int i = 0; i < 2; i++) {
        int g = i * 256 + t; int dl = g >> 3, sg = g & 7;
        alignas(16) ushort_t pk[8];
        #pragma unroll
        for (int j = 0; j < 8; j++) pk[j] = T[sg * 8 + j][dl];
        *(uint4*)&Vt[(size_t)(h * 64 + dl) * S_LEN + s0 + sg * 8] = *(uint4*)pk;
    }
}

// ---------------- bf16 MFMA GEMM 128x128 (QKV projection) ----------------
__global__ __launch_bounds__(256) void gemm_bf16(
    const ushort_t* __restrict__ A, const ushort_t* __restrict__ B,
    ushort_t* __restrict__ Cout, int M, int N, int K)
{
    __shared__ ushort_t As[128 * 64];
    __shared__ ushort_t Bs[128 * 64];
    const int tid = threadIdx.x;
    const int w = tid >> 6, lane = tid & 63, quad = lane >> 4, cid = lane & 15;
    const int wm = w >> 1, wn = w & 1;
    const int m0 = blockIdx.y * 128, n0 = blockIdx.x * 128;

    f32x4 acc[4][4] = {};

    for (int k0 = 0; k0 < K; k0 += 64) {
        #pragma unroll
        for (int i = 0; i < 4; i++) {
            int g = i * 256 + tid; int r = g >> 3, kg = g & 7;
            int dg = kg ^ (r & 7);
            load_lds16(A + (size_t)(m0 + r) * K + k0 + dg * 8, &As[(i * 256 + w * 64) * 8]);
            load_lds16(B + (size_t)(n0 + r) * K + k0 + dg * 8, &Bs[(i * 256 + w * 64) * 8]);
        }
        __syncthreads();
        #pragma unroll
        for (int kk = 0; kk < 2; kk++) {
            bf16x8 af[4], bf[4];
            #pragma unroll
            for (int t = 0; t < 4; t++) {
                int m = wm * 64 + t * 16 + cid;
                af[t] = *(const bf16x8*)&As[m * 64 + (((kk * 4 + quad) ^ (m & 7)) * 8)];
                int n = wn * 64 + t * 16 + cid;
                bf[t] = *(const bf16x8*)&Bs[n * 64 + (((kk * 4 + quad) ^ (n & 7)) * 8)];
            }
            #pragma unroll
            for (int i = 0; i < 4; i++)
                #pragma unroll
                for (int j = 0; j < 4; j++)
                    acc[i][j] = __builtin_amdgcn_mfma_f32_16x16x32_bf16(af[i], bf[j], acc[i][j], 0, 0, 0);
        }
        __syncthreads();
    }
    #pragma unroll
    for (int i = 0; i < 4; i++)
        #pragma unroll
        for (int j = 0; j < 4; j++)
            #pragma unroll
            for (int r = 0; r < 4; r++) {
                int row = m0 + wm * 64 + i * 16 + quad * 4 + r;
                int col = n0 + wn * 64 + j * 16 + cid;
                Cout[(size_t)row * N + col] = f2bf(acc[i][j][r]);
            }
}

// ---------------- bf16 MFMA GEMM 64x64, fp32 out (output projection) ----------------
__global__ __launch_bounds__(256) void gemm64_f32(
    const ushort_t* __restrict__ A, const ushort_t* __restrict__ B,
    float* __restrict__ Cout, int M, int N, int K)
{
    __shared__ ushort_t As[64 * 64];
    __shared__ ushort_t Bs[64 * 64];
    const int tid = threadIdx.x;
    const int w = tid >> 6, lane = tid & 63, quad = lane >> 4, cid = lane & 15;
    const int wm = w >> 1, wn = w & 1;
    const int m0 = blockIdx.y * 64, n0 = blockIdx.x * 64;

    f32x4 acc[2][2] = {};

    for (int k0 = 0; k0 < K; k0 += 64) {
        #pragma unroll
        for (int i = 0; i < 2; i++) {
            int g = i * 256 + tid; int r = g >> 3, kg = g & 7;
            int dg = kg ^ (r & 7);
            load_lds16(A + (size_t)(m0 + r) * K + k0 + dg * 8, &As[(i * 256 + w * 64) * 8]);
            load_lds16(B + (size_t)(n0 + r) * K + k0 + dg * 8, &Bs[(i * 256 + w * 64) * 8]);
        }
        __syncthreads();
        #pragma unroll
        for (int kk = 0; kk < 2; kk++) {
            bf16x8 af[2], bf[2];
            #pragma unroll
            for (int t = 0; t < 2; t++) {
                int m = wm * 32 + t * 16 + cid;
                af[t] = *(const bf16x8*)&As[m * 64 + (((kk * 4 + quad) ^ (m & 7)) * 8)];
                int n = wn * 32 + t * 16 + cid;
                bf[t] = *(const bf16x8*)&Bs[n * 64 + (((kk * 4 + quad) ^ (n & 7)) * 8)];
            }
            #pragma unroll
            for (int i = 0; i < 2; i++)
                #pragma unroll
                for (int j = 0; j < 2; j++)
                    acc[i][j] = __builtin_amdgcn_mfma_f32_16x16x32_bf16(af[i], bf[j], acc[i][j], 0, 0, 0);
        }
        __syncthreads();
    }
    #pragma unroll
    for (int i = 0; i < 2; i++)
        #pragma unroll
        for (int j = 0; j < 2; j++)
            #pragma unroll
            for (int r = 0; r < 4; r++) {
                int row = m0 + wm * 32 + i * 16 + quad * 4 + r;
                int col = n0 + wn * 32 + j * 16 + cid;
                Cout[(size_t)row * N + col] = acc[i][j][r];
            }
}

// ---------------- MFMA flash attention, fixed-max (m=0) ----------------
// Block: 1 head x 64 queries, 4 waves (16 q-rows each). K-chunks of 64.
// p = exp(s + bias) unscaled; l accumulated via all-ones-B MFMA; O/l at end.
__global__ __launch_bounds__(256) void attn_mfma(
    const ushort_t* __restrict__ QKV, const ushort_t* __restrict__ Vt,
    const float* __restrict__ rel_bias, ushort_t* __restrict__ Ctx)
{
    __shared__ float    tab[4096];       // bias[j = q - k + 2047], 16 KB
    __shared__ ushort_t Ks[64 * 64];     // [key][dgran ^ key&7]     8 KB
    __shared__ ushort_t Vs[64 * 64];     // [d][keygran ^ d&7]       8 KB
    __shared__ ushort_t Ps[4][16 * 64];  // per-wave, wave-private   8 KB

    const int tid = threadIdx.x;
    const int w = tid >> 6, lane = tid & 63, quad = lane >> 4, cid = lane & 15;
    const int h = blockIdx.y, q0 = blockIdx.x * 64;

    // exact-integer bias table init (once per block)
    for (int idx = tid; idx < 4095; idx += 256)
        tab[idx] = rel_bias[rel_bucket(2047 - idx) * NH + h];

    const int qg = q0 + w * 16 + cid;
    bf16x8 qf[2];
    #pragma unroll
    for (int kk = 0; kk < 2; kk++)
        qf[kk] = *(const bf16x8*)&QKV[(size_t)qg * QKV_LD + h * 64 + kk * 32 + quad * 8];

    bf16x8 vones;
    {
        union { ushort_t u; __bf16 b; } c; c.u = 0x3F80;  // bf16 1.0
        #pragma unroll
        for (int i = 0; i < 8; i++) vones[i] = c.b;
    }

    f32x4 Oacc[4] = {};   // rows quad*4+r, col dt*16+cid
    f32x4 Lacc = {};      // l for rows quad*4+r (all cols identical)

    // lane-constant part of bias index, rebased so all imm offsets >= 0
    const int jb = (q0 + w * 16 + quad * 4) - cid + 2047 - 48;

    for (int k0 = 0; k0 < S_LEN; k0 += 64) {
        __syncthreads();   // prior chunk's Ks/Vs reads done (1st iter: tab init)
        #pragma unroll
        for (int i = 0; i < 2; i++) {
            int g = i * 256 + tid; int row = g >> 3, kg = g & 7;
            load_lds16(QKV + (size_t)(k0 + row) * QKV_LD + 1024 + h * 64 + ((kg ^ (row & 7)) * 8),
                       &Ks[(i * 256 + w * 64) * 8]);
            load_lds16(Vt + (size_t)(h * 64 + row) * S_LEN + k0 + ((kg ^ (row & 7)) * 8),
                       &Vs[(i * 256 + w * 64) * 8]);
        }
        __syncthreads();

        // S = Q K^T  (per wave: 16q x 64key in 4 tiles)
        f32x4 S[4] = {};
        #pragma unroll
        for (int kk = 0; kk < 2; kk++)
            #pragma unroll
            for (int tj = 0; tj < 4; tj++) {
                int key = tj * 16 + cid;
                bf16x8 kf = *(const bf16x8*)&Ks[key * 64 + (((kk * 4 + quad) ^ (key & 7)) * 8)];
                S[tj] = __builtin_amdgcn_mfma_f32_16x16x32_bf16(qf[kk], kf, S[tj], 0, 0, 0);
            }

        // p = exp(s + bias); store bf16 to wave-private Ps (A-operand layout)
        const float* tb = &tab[jb - k0];
        #pragma unroll
        for (int tj = 0; tj < 4; tj++) {
            #pragma unroll
            for (int r = 0; r < 4; r++) {
                float p = __expf(S[tj][r] + tb[48 - tj * 16 + r]);
                int qloc = quad * 4 + r;
                int kgr = (tj * 2 + (cid >> 3)) ^ (qloc & 7);
                Ps[w][qloc * 64 + kgr * 8 + (cid & 7)] = f2bf_rn(p);
            }
        }
        // wave-private LDS: no barrier needed (lgkmcnt ordering within wave)

        bf16x8 pf[2];
        #pragma unroll
        for (int kk = 0; kk < 2; kk++)
            pf[kk] = *(const bf16x8*)&Ps[w][cid * 64 + (((kk * 4 + quad) ^ (cid & 7)) * 8)];

        // l += P @ 1 (2 MFMA, no DS, no shuffles)
        #pragma unroll
        for (int kk = 0; kk < 2; kk++)
            Lacc = __builtin_amdgcn_mfma_f32_16x16x32_bf16(pf[kk], vones, Lacc, 0, 0, 0);

        // O += P @ V
        #pragma unroll
        for (int kk = 0; kk < 2; kk++)
            #pragma unroll
            for (int dt = 0; dt < 4; dt++) {
                int d = dt * 16 + cid;
                bf16x8 vf = *(const bf16x8*)&Vs[d * 64 + (((kk * 4 + quad) ^ (d & 7)) * 8)];
                Oacc[dt] = __builtin_amdgcn_mfma_f32_16x16x32_bf16(pf[kk], vf, Oacc[dt], 0, 0, 0);
            }
    }

    #pragma unroll
    for (int r = 0; r < 4; r++) {
        float inv = 1.f / Lacc[r];
        int row = q0 + w * 16 + quad * 4 + r;
        #pragma unroll
        for (int dt = 0; dt < 4; dt++)
            Ctx[(size_t)row * DMODEL + h * 64 + dt * 16 + cid] = f2bf(Oacc[dt][r] * inv);
    }
}

// ---------------- launch ----------------
extern "C" void kernel_launch(void* const* d_in, const int* in_sizes, int n_in,
                              void* d_out, int out_size, void* d_ws, size_t ws_size,
                              hipStream_t stream) {
    const float* X  = (const float*)d_in[0];
    const float* Wq = (const float*)d_in[1];
    const float* Wk = (const float*)d_in[2];
    const float* Wv = (const float*)d_in[3];
    const float* Wo = (const float*)d_in[4];
    const float* rb = (const float*)d_in[5];
    float* out = (float*)d_out;

    ushort_t* ws = (ushort_t*)d_ws;
    const size_t M1 = 1024 * 1024;
    ushort_t* Xb  = ws;             // 2M elems; reused as Ctx after QKV GEMM
    ushort_t* Wt  = ws + 2 * M1;    // 3M elems  [3072][1024] = Wq^T|Wk^T|Wv^T
    ushort_t* Wot = ws + 5 * M1;    // 1M elems
    ushort_t* QKV = ws + 6 * M1;    // 6M elems  [2048][3072] bf16
    ushort_t* Vt  = ws + 12 * M1;   // 2M elems  [16][64][2048]
    ushort_t* Ctx = Xb;

    cast_x<<<dim3((S_LEN * DMODEL / 4 + 255) / 256), 256, 0, stream>>>(X, Xb, S_LEN * DMODEL / 4);
    wcast<<<dim3(16, 16, 4), 256, 0, stream>>>(Wq, Wk, Wv, Wo, Wt, Wot);
    gemm_bf16<<<dim3(24, 16), 256, 0, stream>>>(Xb, Wt, QKV, S_LEN, 3072, DMODEL);
    vt_trans<<<dim3(32, 16), 256, 0, stream>>>(QKV, Vt);
    attn_mfma<<<dim3(32, 16), 256, 0, stream>>>(QKV, Vt, rb, Ctx);
    gemm64_f32<<<dim3(16, 32), 256, 0, stream>>>(Ctx, Wot, out, S_LEN, DMODEL, DMODEL);
}

// Round 4
// 160.746 us; speedup vs baseline: 5.2924x; 1.0736x over previous
//
#include <hip/hip_runtime.h>
#include <cstddef>
#include <cstdint>

typedef float  f32x4  __attribute__((ext_vector_type(4)));
typedef __bf16 bf16x8 __attribute__((ext_vector_type(8)));
typedef unsigned short ushort_t;
typedef unsigned int __attribute__((address_space(1))) u32_g;
typedef unsigned int __attribute__((address_space(3))) u32_l;

#define S_LEN  2048
#define DMODEL 1024
#define NH     16
#define QKV_LD 3072   // fused QKV row stride (Q|K|V)

static __device__ __forceinline__ ushort_t f2bf(float f) {
    union { float f; unsigned u; } v; v.f = f;
    unsigned r = (v.u + 0x7FFFu + ((v.u >> 16) & 1u)) >> 16;
    return (ushort_t)r;
}
static __device__ __forceinline__ float bf2f(ushort_t b) {
    union { unsigned u; float f; } v; v.u = ((unsigned)b) << 16;
    return v.f;
}
// fast round-to-nearest (no tie-even) — valid for positive finite p
static __device__ __forceinline__ ushort_t f2bf_rn(float f) {
    union { float f; unsigned u; } v; v.f = f;
    return (ushort_t)((v.u + 0x8000u) >> 16);
}
// async 16B global->LDS; lds dst = wave-uniform base + lane*16
static __device__ __forceinline__ void load_lds16(const void* g, void* l) {
    __builtin_amdgcn_global_load_lds((const u32_g*)g, (u32_l*)l, 16, 0, 0);
}
static __device__ __forceinline__ int rel_bucket(int rp) {
    int arp = rp < 0 ? -rp : rp;
    int bucket;
    if (arp < 8) bucket = arp;
    else { int lg = 33 - __clz(arp * arp); bucket = lg < 15 ? lg : 15; }
    return rp > 0 ? bucket + 16 : bucket;
}

// ---------------- cast X (fp32 -> bf16), elementwise ----------------
__global__ __launch_bounds__(256) void cast_x(const float* __restrict__ X,
                                              ushort_t* __restrict__ Xb, int n4) {
    int i = blockIdx.x * 256 + threadIdx.x;
    if (i < n4) {
        float4 v = ((const float4*)X)[i];
        ushort4 o = make_ushort4(f2bf(v.x), f2bf(v.y), f2bf(v.z), f2bf(v.w));
        ((ushort4*)Xb)[i] = o;
    }
}

// ------------- weight transpose+cast: W[k][n] fp32 -> W^T[n][k] bf16 -------------
__global__ __launch_bounds__(256) void wcast(
    const float* __restrict__ Wq, const float* __restrict__ Wk,
    const float* __restrict__ Wv, const float* __restrict__ Wo,
    ushort_t* __restrict__ Wt, ushort_t* __restrict__ Wot)
{
    __shared__ float T[64][68];
    const int z = blockIdx.z;
    const float* W = (z == 0) ? Wq : (z == 1) ? Wk : (z == 2) ? Wv : Wo;
    ushort_t* Out = (z == 3) ? Wot : (Wt + (size_t)z * 1024 * 1024);
    const int k0 = blockIdx.y * 64, n0 = blockIdx.x * 64;
    const int t = threadIdx.x;
    #pragma unroll
    for (int i = 0; i < 4; i++) {
        int g = i * 256 + t; int kl = g >> 4, ng = g & 15;
        float4 v = *(const float4*)&W[(size_t)(k0 + kl) * 1024 + n0 + ng * 4];
        *(float4*)&T[kl][ng * 4] = v;
    }
    __syncthreads();
    #pragma unroll
    for (int i = 0; i < 2; i++) {
        int g = i * 256 + t; int nl = g >> 3, kg = g & 7;
        alignas(16) ushort_t pk[8];
        #pragma unroll
        for (int j = 0; j < 8; j++) pk[j] = f2bf(T[kg * 8 + j][nl]);
        *(uint4*)&Out[(size_t)(n0 + nl) * 1024 + k0 + kg * 8] = *(uint4*)pk;
    }
}

// ------------- per-head V transpose: QKV V-section -> Vt[h][d][s] bf16 -------------
__global__ __launch_bounds__(256) void vt_trans(const ushort_t* __restrict__ QKV,
                                                ushort_t* __restrict__ Vt) {
    __shared__ ushort_t T[64][80];
    const int h = blockIdx.y, s0 = blockIdx.x * 64;
    const int t = threadIdx.x;
    #pragma unroll
    for (int i = 0; i < 2; i++) {
        int g = i * 256 + t; int sl = g >> 3, dg = g & 7;
        *(uint4*)&T[sl][dg * 8] =
            *(const uint4*)&QKV[(size_t)(s0 + sl) * QKV_LD + 2048 + h * 64 + dg * 8];
    }
    __syncthreads();
    #pragma unroll
    for (int i = 0; i < 2; i++) {
        int g = i * 256 + t; int dl = g >> 3, sg = g & 7;
        alignas(16) ushort_t pk[8];
        #pragma unroll
        for (int j = 0; j < 8; j++) pk[j] = T[sg * 8 + j][dl];
        *(uint4*)&Vt[(size_t)(h * 64 + dl) * S_LEN + s0 + sg * 8] = *(uint4*)pk;
    }
}

// ---------------- bf16 MFMA GEMM 128x128 (QKV projection) ----------------
__global__ __launch_bounds__(256) void gemm_bf16(
    const ushort_t* __restrict__ A, const ushort_t* __restrict__ B,
    ushort_t* __restrict__ Cout, int M, int N, int K)
{
    __shared__ ushort_t As[128 * 64];
    __shared__ ushort_t Bs[128 * 64];
    const int tid = threadIdx.x;
    const int w = tid >> 6, lane = tid & 63, quad = lane >> 4, cid = lane & 15;
    const int wm = w >> 1, wn = w & 1;
    const int m0 = blockIdx.y * 128, n0 = blockIdx.x * 128;

    f32x4 acc[4][4] = {};

    for (int k0 = 0; k0 < K; k0 += 64) {
        #pragma unroll
        for (int i = 0; i < 4; i++) {
            int g = i * 256 + tid; int r = g >> 3, kg = g & 7;
            int dg = kg ^ (r & 7);
            load_lds16(A + (size_t)(m0 + r) * K + k0 + dg * 8, &As[(i * 256 + w * 64) * 8]);
            load_lds16(B + (size_t)(n0 + r) * K + k0 + dg * 8, &Bs[(i * 256 + w * 64) * 8]);
        }
        __syncthreads();
        #pragma unroll
        for (int kk = 0; kk < 2; kk++) {
            bf16x8 af[4], bf[4];
            #pragma unroll
            for (int t = 0; t < 4; t++) {
                int m = wm * 64 + t * 16 + cid;
                af[t] = *(const bf16x8*)&As[m * 64 + (((kk * 4 + quad) ^ (m & 7)) * 8)];
                int n = wn * 64 + t * 16 + cid;
                bf[t] = *(const bf16x8*)&Bs[n * 64 + (((kk * 4 + quad) ^ (n & 7)) * 8)];
            }
            #pragma unroll
            for (int i = 0; i < 4; i++)
                #pragma unroll
                for (int j = 0; j < 4; j++)
                    acc[i][j] = __builtin_amdgcn_mfma_f32_16x16x32_bf16(af[i], bf[j], acc[i][j], 0, 0, 0);
        }
        __syncthreads();
    }
    #pragma unroll
    for (int i = 0; i < 4; i++)
        #pragma unroll
        for (int j = 0; j < 4; j++)
            #pragma unroll
            for (int r = 0; r < 4; r++) {
                int row = m0 + wm * 64 + i * 16 + quad * 4 + r;
                int col = n0 + wn * 64 + j * 16 + cid;
                Cout[(size_t)row * N + col] = f2bf(acc[i][j][r]);
            }
}

// ---------------- bf16 MFMA GEMM 64x64, fp32 out (output projection) ----------------
__global__ __launch_bounds__(256) void gemm64_f32(
    const ushort_t* __restrict__ A, const ushort_t* __restrict__ B,
    float* __restrict__ Cout, int M, int N, int K)
{
    __shared__ ushort_t As[64 * 64];
    __shared__ ushort_t Bs[64 * 64];
    const int tid = threadIdx.x;
    const int w = tid >> 6, lane = tid & 63, quad = lane >> 4, cid = lane & 15;
    const int wm = w >> 1, wn = w & 1;
    const int m0 = blockIdx.y * 64, n0 = blockIdx.x * 64;

    f32x4 acc[2][2] = {};

    for (int k0 = 0; k0 < K; k0 += 64) {
        #pragma unroll
        for (int i = 0; i < 2; i++) {
            int g = i * 256 + tid; int r = g >> 3, kg = g & 7;
            int dg = kg ^ (r & 7);
            load_lds16(A + (size_t)(m0 + r) * K + k0 + dg * 8, &As[(i * 256 + w * 64) * 8]);
            load_lds16(B + (size_t)(n0 + r) * K + k0 + dg * 8, &Bs[(i * 256 + w * 64) * 8]);
        }
        __syncthreads();
        #pragma unroll
        for (int kk = 0; kk < 2; kk++) {
            bf16x8 af[2], bf[2];
            #pragma unroll
            for (int t = 0; t < 2; t++) {
                int m = wm * 32 + t * 16 + cid;
                af[t] = *(const bf16x8*)&As[m * 64 + (((kk * 4 + quad) ^ (m & 7)) * 8)];
                int n = wn * 32 + t * 16 + cid;
                bf[t] = *(const bf16x8*)&Bs[n * 64 + (((kk * 4 + quad) ^ (n & 7)) * 8)];
            }
            #pragma unroll
            for (int i = 0; i < 2; i++)
                #pragma unroll
                for (int j = 0; j < 2; j++)
                    acc[i][j] = __builtin_amdgcn_mfma_f32_16x16x32_bf16(af[i], bf[j], acc[i][j], 0, 0, 0);
        }
        __syncthreads();
    }
    #pragma unroll
    for (int i = 0; i < 2; i++)
        #pragma unroll
        for (int j = 0; j < 2; j++)
            #pragma unroll
            for (int r = 0; r < 4; r++) {
                int row = m0 + wm * 32 + i * 16 + quad * 4 + r;
                int col = n0 + wn * 32 + j * 16 + cid;
                Cout[(size_t)row * N + col] = acc[i][j][r];
            }
}

// ---------------- MFMA flash attention, fixed-max (m=0), split-K=2 ----------------
// Grid (32, 16, 2): q-tile, head, K-segment of 1024. Block: 4 waves x 16 q-rows.
// Writes UNNORMALIZED partial O (bf16) and partial l (fp32); reduce combines.
__global__ __launch_bounds__(256) void attn_mfma(
    const ushort_t* __restrict__ QKV, const ushort_t* __restrict__ Vt,
    const float* __restrict__ rel_bias,
    ushort_t* __restrict__ Opart, float* __restrict__ Lpart)
{
    __shared__ float    tab[1088];       // bias over this block's rp span, 4.25 KB
    __shared__ ushort_t Ks[64 * 64];     // [key][dgran ^ key&7]     8 KB
    __shared__ ushort_t Vs[64 * 64];     // [d][keygran ^ d&7]       8 KB
    __shared__ ushort_t Ps[4][16 * 64];  // per-wave, wave-private   8 KB

    const int tid = threadIdx.x;
    const int w = tid >> 6, lane = tid & 63, quad = lane >> 4, cid = lane & 15;
    const int h = blockIdx.y, q0 = blockIdx.x * 64;
    const int seg = blockIdx.z, s0 = seg * 1024;
    const int wq4 = w * 16 + quad * 4;

    // bias table for rp = k - q in [s0 - q0 - 63, s0 + 1023 - q0]
    const int rpmin = s0 - q0 - 63;
    for (int idx = tid; idx < 1087; idx += 256)
        tab[idx] = rel_bias[rel_bucket(rpmin + idx) * NH + h];

    const int qg = q0 + w * 16 + cid;
    bf16x8 qf[2];
    #pragma unroll
    for (int kk = 0; kk < 2; kk++)
        qf[kk] = *(const bf16x8*)&QKV[(size_t)qg * QKV_LD + h * 64 + kk * 32 + quad * 8];

    bf16x8 vones;
    {
        union { ushort_t u; __bf16 b; } c; c.u = 0x3F80;  // bf16 1.0
        #pragma unroll
        for (int i = 0; i < 8; i++) vones[i] = c.b;
    }

    f32x4 Oacc[4] = {};   // rows quad*4+r, col dt*16+cid
    f32x4 Lacc = {};      // l for rows quad*4+r (all cols identical)

    for (int k0 = s0; k0 < s0 + 1024; k0 += 64) {
        __syncthreads();   // prior chunk's Ks/Vs reads done (1st iter: tab init)
        #pragma unroll
        for (int i = 0; i < 2; i++) {
            int g = i * 256 + tid; int row = g >> 3, kg = g & 7;
            load_lds16(QKV + (size_t)(k0 + row) * QKV_LD + 1024 + h * 64 + ((kg ^ (row & 7)) * 8),
                       &Ks[(i * 256 + w * 64) * 8]);
            load_lds16(Vt + (size_t)(h * 64 + row) * S_LEN + k0 + ((kg ^ (row & 7)) * 8),
                       &Vs[(i * 256 + w * 64) * 8]);
        }
        __syncthreads();

        // S = Q K^T  (per wave: 16q x 64key in 4 tiles)
        f32x4 S[4] = {};
        #pragma unroll
        for (int kk = 0; kk < 2; kk++)
            #pragma unroll
            for (int tj = 0; tj < 4; tj++) {
                int key = tj * 16 + cid;
                bf16x8 kf = *(const bf16x8*)&Ks[key * 64 + (((kk * 4 + quad) ^ (key & 7)) * 8)];
                S[tj] = __builtin_amdgcn_mfma_f32_16x16x32_bf16(qf[kk], kf, S[tj], 0, 0, 0);
            }

        // p = exp(s + bias); store bf16 to wave-private Ps (A-operand layout)
        // idx(tj,r) = (k0-s0) + cid - wq4 + 63 + tj*16 - r ; offsets >= 0 via -3 rebase
        const float* tbp = &tab[(k0 - s0) + cid - wq4 + 60];
        #pragma unroll
        for (int tj = 0; tj < 4; tj++) {
            #pragma unroll
            for (int r = 0; r < 4; r++) {
                float p = __expf(S[tj][r] + tbp[tj * 16 - r + 3]);
                int qloc = quad * 4 + r;
                int kgr = (tj * 2 + (cid >> 3)) ^ (qloc & 7);
                Ps[w][qloc * 64 + kgr * 8 + (cid & 7)] = f2bf_rn(p);
            }
        }
        // wave-private LDS: no barrier needed (lgkmcnt ordering within wave)

        bf16x8 pf[2];
        #pragma unroll
        for (int kk = 0; kk < 2; kk++)
            pf[kk] = *(const bf16x8*)&Ps[w][cid * 64 + (((kk * 4 + quad) ^ (cid & 7)) * 8)];

        // l += P @ 1 (2 MFMA, no DS, no shuffles)
        #pragma unroll
        for (int kk = 0; kk < 2; kk++)
            Lacc = __builtin_amdgcn_mfma_f32_16x16x32_bf16(pf[kk], vones, Lacc, 0, 0, 0);

        // O += P @ V
        #pragma unroll
        for (int kk = 0; kk < 2; kk++)
            #pragma unroll
            for (int dt = 0; dt < 4; dt++) {
                int d = dt * 16 + cid;
                bf16x8 vf = *(const bf16x8*)&Vs[d * 64 + (((kk * 4 + quad) ^ (d & 7)) * 8)];
                Oacc[dt] = __builtin_amdgcn_mfma_f32_16x16x32_bf16(pf[kk], vf, Oacc[dt], 0, 0, 0);
            }
    }

    // partial l (lane cid==0 holds rows wq4..wq4+3; all cid copies identical)
    if (cid == 0) {
        #pragma unroll
        for (int r = 0; r < 4; r++)
            Lpart[((size_t)seg * NH + h) * S_LEN + q0 + wq4 + r] = Lacc[r];
    }
    // partial O, bf16, unnormalized
    #pragma unroll
    for (int r = 0; r < 4; r++) {
        int row = q0 + wq4 + r;
        #pragma unroll
        for (int dt = 0; dt < 4; dt++)
            Opart[(size_t)seg * (S_LEN * DMODEL) + (size_t)row * DMODEL + h * 64 + dt * 16 + cid]
                = f2bf(Oacc[dt][r]);
    }
}

// ---------------- combine split-K partials: Ctx = (O0+O1)/(l0+l1) ----------------
__global__ __launch_bounds__(256) void attn_reduce(
    const ushort_t* __restrict__ Opart, const float* __restrict__ Lpart,
    ushort_t* __restrict__ Ctx)
{
    int i = blockIdx.x * 256 + threadIdx.x;   // over 2048*1024/8 uint4-of-bf16
    int row = i >> 7;                          // 128 x 8 elems per row
    int h = (i & 127) >> 3;
    float l = Lpart[h * S_LEN + row] + Lpart[(NH + h) * S_LEN + row];
    float inv = 1.f / l;
    uint4 a = ((const uint4*)Opart)[i];
    uint4 b = ((const uint4*)Opart)[i + S_LEN * DMODEL / 8];
    alignas(16) ushort_t oa[8]; *(uint4*)oa = a;
    alignas(16) ushort_t ob[8]; *(uint4*)ob = b;
    alignas(16) ushort_t oc[8];
    #pragma unroll
    for (int j = 0; j < 8; j++) oc[j] = f2bf((bf2f(oa[j]) + bf2f(ob[j])) * inv);
    ((uint4*)Ctx)[i] = *(uint4*)oc;
}

// ---------------- launch ----------------
extern "C" void kernel_launch(void* const* d_in, const int* in_sizes, int n_in,
                              void* d_out, int out_size, void* d_ws, size_t ws_size,
                              hipStream_t stream) {
    const float* X  = (const float*)d_in[0];
    const float* Wq = (const float*)d_in[1];
    const float* Wk = (const float*)d_in[2];
    const float* Wv = (const float*)d_in[3];
    const float* Wo = (const float*)d_in[4];
    const float* rb = (const float*)d_in[5];
    float* out = (float*)d_out;

    ushort_t* ws = (ushort_t*)d_ws;
    const size_t M1 = 1024 * 1024;
    // Region timeline (ushort units, 14M total = 28 MB):
    //  0..2M   Xb (bf16 X)        -> dead after QKV gemm -> Opart seg0/seg1 (0..4M)
    //  2..5M   Wt                 -> dead after QKV gemm -> Opart tail + Lpart
    //  5..6M   Wot                (live until final gemm)
    //  6..12M  QKV                -> dead after attn     -> Ctx at 6..8M
    // 12..14M  Vt                 -> dead after attn
    ushort_t* Xb    = ws;
    ushort_t* Wt    = ws + 2 * M1;
    ushort_t* Wot   = ws + 5 * M1;
    ushort_t* QKV   = ws + 6 * M1;
    ushort_t* Vt    = ws + 12 * M1;
    ushort_t* Opart = ws;                       // 4M ushort (2 segs x 2M), over Xb/Wt
    float*    Lpart = (float*)(ws + 4 * M1);    // 64K floats, within dead Wt region
    ushort_t* Ctx   = ws + 6 * M1;              // 2M ushort, over dead QKV

    cast_x<<<dim3((S_LEN * DMODEL / 4 + 255) / 256), 256, 0, stream>>>(X, Xb, S_LEN * DMODEL / 4);
    wcast<<<dim3(16, 16, 4), 256, 0, stream>>>(Wq, Wk, Wv, Wo, Wt, Wot);
    gemm_bf16<<<dim3(24, 16), 256, 0, stream>>>(Xb, Wt, QKV, S_LEN, 3072, DMODEL);
    vt_trans<<<dim3(32, 16), 256, 0, stream>>>(QKV, Vt);
    attn_mfma<<<dim3(32, 16, 2), 256, 0, stream>>>(QKV, Vt, rb, Opart, Lpart);
    attn_reduce<<<dim3(S_LEN * DMODEL / 8 / 256), 256, 0, stream>>>(Opart, Lpart, Ctx);
    gemm64_f32<<<dim3(16, 32), 256, 0, stream>>>(Ctx, Wot, out, S_LEN, DMODEL, DMODEL);
}